// Round 1
// baseline (523.441 us; speedup 1.0000x reference)
//
#include <hip/hip_runtime.h>

// Problem constants (from reference setup_inputs)
#define BB 8      // batch
#define RR 16     // rotations
#define NN 6144   // gpc systems (vertices)
#define FF 128    // features

// Native clang vector type — required for __builtin_nontemporal_store.
typedef float f32x4 __attribute__((ext_vector_type(4)));

// Quarter-wave (16 lanes) per (b, n) row; one wave handles 4 consecutive rows.
// Each lane owns 8 features as two coalesced dwordx4 groups:
//   group A: features [sublane*4 .. sublane*4+4)         (row bytes   0..255)
//   group B: features [64 + sublane*4 .. 64+sublane*4+4) (row bytes 256..511)
//
// Phase 1: per rotation, 2 coalesced 16B/lane loads, per-lane sum of 8
//   squares, 4-level butterfly (xor 1,2,4,8 — stays inside each 16-lane
//   quarter), track ONLY best_sum + best_r (strict '>' keeps the FIRST max,
//   matching jnp.argmax tie-break). No vector select state -> low VGPR.
// Phase 2: reload the winning rotation's 2 vectors (cached loads; the data
//   was streamed by this wave moments ago -> expected L3 hit) and store.
//
// __launch_bounds__(256, 8): 8 waves/SIMD minimum -> VGPR cap 64. Phase-1
// body needs ~40 VGPRs at unroll 4, so no spill expected; max occupancy
// restores latency hiding (prev version: full unroll + 8-reg select state
// suspected to have crushed occupancy -> 0.86 TB/s).
__global__ __launch_bounds__(256, 8) void amp_kernel(const float* __restrict__ in,
                                                     float* __restrict__ out) {
    const int tid     = blockIdx.x * 256 + threadIdx.x;
    const int wave    = tid >> 6;        // global wave id = group of 4 rows
    const int lane    = tid & 63;
    const int quarter = lane >> 4;       // 0..3: which row within the wave
    const int sublane = lane & 15;       // feature group within row

    const int b     = wave / (NN / 4);
    const int n_grp = wave - b * (NN / 4);
    const int n     = n_grp * 4 + quarter;

    // &in[b][0][n][sublane*4]
    const size_t base    = (((size_t)b * RR) * NN + n) * (size_t)FF + (sublane << 2);
    const size_t rstride = (size_t)NN * FF;   // stride between rotations

    float best_sum = -1.f;                    // sums >= 0, so r=0 always wins first
    int   best_r   = 0;

    const float* p = in + base;
    #pragma unroll 4
    for (int r = 0; r < RR; ++r) {
        const f32x4 va = *(const f32x4*)p;
        const f32x4 vb = *(const f32x4*)(p + 64);
        p += rstride;
        float s = va.x * va.x + va.y * va.y + va.z * va.z + va.w * va.w
                + vb.x * vb.x + vb.y * vb.y + vb.z * vb.z + vb.w * vb.w;
        // 16-lane butterfly sum (stays within each quarter of the wave)
        s += __shfl_xor(s, 1);
        s += __shfl_xor(s, 2);
        s += __shfl_xor(s, 4);
        s += __shfl_xor(s, 8);
        if (s > best_sum) {                   // strict: first max wins, like argmax
            best_sum = s;
            best_r   = r;
        }
    }

    // Phase 2: reload winner (expected L3-hit; read moments ago by this wave)
    const float* q = in + base + (size_t)best_r * rstride;
    const f32x4 wa = *(const f32x4*)q;
    const f32x4 wb = *(const f32x4*)(q + 64);

    // &out[b][n][sublane*4]
    float* o = out + ((size_t)b * NN + n) * (size_t)FF + (sublane << 2);
    __builtin_nontemporal_store(wa, (f32x4*)o);
    __builtin_nontemporal_store(wb, (f32x4*)(o + 64));
}

extern "C" void kernel_launch(void* const* d_in, const int* in_sizes, int n_in,
                              void* d_out, int out_size, void* d_ws, size_t ws_size,
                              hipStream_t stream) {
    const float* in  = (const float*)d_in[0];
    float*       out = (float*)d_out;

    // B*N/4 waves (each wave does 4 rows), 4 waves (256 threads) per block
    const int n_waves  = BB * NN / 4;         // 12288
    const int n_blocks = n_waves / 4;         // 3072

    amp_kernel<<<dim3(n_blocks), dim3(256), 0, stream>>>(in, out);
}